// Round 20
// baseline (691.442 us; speedup 1.0000x reference)
//
#include <hip/hip_runtime.h>

#define G 128
#define N 32
#define H 128
#define L 6

typedef _Float16 half8 __attribute__((ext_vector_type(8)));
typedef float f32x4 __attribute__((ext_vector_type(4)));

union H8 { unsigned u[4]; half8 v; };

__device__ inline unsigned short f16_bits(_Float16 h) {
  union { _Float16 f; unsigned short u; } c; c.f = h; return c.u;
}

// pack fp32 -> (f16 hi) | (f16 lo)<<16, hi = rne(x), lo = rne(x - hi)
__device__ inline unsigned packf16(float x) {
  _Float16 hi = (_Float16)x;
  _Float16 lo = (_Float16)(x - (float)hi);
  return (unsigned)f16_bits(hi) | ((unsigned)f16_bits(lo) << 16);
}

// ---------------------------------------------------------------------------
// HEAD (merged E1 + PW): blocks 0-1 emb mm; blocks 2-193 pack Wc.
// ---------------------------------------------------------------------------
__global__ __launch_bounds__(256) void k_head(
    const float* __restrict__ emb_x,
    const float* __restrict__ W0, const float* __restrict__ b0, float* __restrict__ P0,
    const float* __restrict__ W1, const float* __restrict__ b1, float* __restrict__ P1,
    const float* __restrict__ Wc, unsigned* __restrict__ Whi,
    unsigned* __restrict__ Wlo) {
  int tid = threadIdx.x;
  if (blockIdx.x >= 2) {
    int o  = (blockIdx.x - 2) * 256 + tid;      // 0 .. 49151
    int kp = o & 63;
    int h  = (o >> 6) & 127;
    int l  = o >> 13;
    const float* Wl = Wc + (size_t)l * 16384;
    float a = Wl[(2 * kp) * 128 + h];
    float b = Wl[(2 * kp + 1) * 128 + h];
    unsigned pa = packf16(a), pb = packf16(b);
    Whi[o] = __builtin_amdgcn_perm(pb, pa, 0x05040100u);
    Wlo[o] = __builtin_amdgcn_perm(pb, pa, 0x07060302u);
    return;
  }
  const float* W = blockIdx.x ? W1 : W0;
  const float* b = blockIdx.x ? b1 : b0;
  float*       P = blockIdx.x ? P1 : P0;
  __shared__ float embs_t[128 * 32];   // [k][i]
  {
    int i = tid & 31, k0 = (tid >> 5) * 16;
    const float* src = emb_x + i * 128 + k0;
#pragma unroll
    for (int m = 0; m < 16; m++) embs_t[(k0 + m) * 32 + i] = src[m];
  }
  __syncthreads();
  int i  = tid >> 3;
  int h0 = (tid & 7) * 16;
  float acc[16];
#pragma unroll
  for (int hh = 0; hh < 16; hh++) acc[hh] = b[h0 + hh];
  for (int k = 0; k < 128; k++) {
    float a = embs_t[k * 32 + i];
    const float4* wr = (const float4*)(W + k * 128 + h0);
    float4 w0 = wr[0], w1 = wr[1], w2 = wr[2], w3 = wr[3];
    acc[0]  += a * w0.x; acc[1]  += a * w0.y; acc[2]  += a * w0.z; acc[3]  += a * w0.w;
    acc[4]  += a * w1.x; acc[5]  += a * w1.y; acc[6]  += a * w1.z; acc[7]  += a * w1.w;
    acc[8]  += a * w2.x; acc[9]  += a * w2.y; acc[10] += a * w2.z; acc[11] += a * w2.w;
    acc[12] += a * w3.x; acc[13] += a * w3.y; acc[14] += a * w3.z; acc[15] += a * w3.w;
  }
  float4* dst = (float4*)(P + i * 128 + h0);
  dst[0] = make_float4(acc[0], acc[1], acc[2], acc[3]);
  dst[1] = make_float4(acc[4], acc[5], acc[6], acc[7]);
  dst[2] = make_float4(acc[8], acc[9], acc[10], acc[11]);
  dst[3] = make_float4(acc[12], acc[13], acc[14], acc[15]);
}

// ---------------------------------------------------------------------------
// E2: build X h-planar: Xp[g][h][i*32+j]. One WG per graph.
// ---------------------------------------------------------------------------
__global__ __launch_bounds__(256) void k_buildX(
    const int* __restrict__ x_idx, const int* __restrict__ tf_idx,
    const float* __restrict__ P0, const float* __restrict__ P1,
    const float* __restrict__ emb_tf, float* __restrict__ Xp) {
  int g = blockIdx.x, tid = threadIdx.x;
  __shared__ float x0t[128 * 32];
  __shared__ float x1t[128 * 32];
  __shared__ float etf[128 * 16];
  __shared__ int   tfs[1024];
  {
    int i = tid & 31, h0 = (tid >> 5) * 16;
    int r = x_idx[g * 32 + i];
    const float* s0 = P0 + r * 128 + h0;
    const float* s1 = P1 + r * 128 + h0;
#pragma unroll
    for (int m = 0; m < 16; m++) {
      x0t[(h0 + m) * 32 + i] = s0[m];
      x1t[(h0 + m) * 32 + i] = s1[m];
    }
  }
  {
    int t = tid & 15, h0 = (tid >> 4) * 8;
    const float* s = emb_tf + t * 128 + h0;
#pragma unroll
    for (int m = 0; m < 8; m++) etf[(h0 + m) * 16 + t] = s[m];
  }
  ((int4*)tfs)[tid] = ((const int4*)(tf_idx + (size_t)g * 1024))[tid];
  __syncthreads();
  int i = tid >> 3, j0 = (tid & 7) * 4;
  int t0 = tfs[i * 32 + j0 + 0], t1 = tfs[i * 32 + j0 + 1];
  int t2 = tfs[i * 32 + j0 + 2], t3 = tfs[i * 32 + j0 + 3];
  float* outg = Xp + ((size_t)g << 17);
  for (int h = 0; h < 128; h++) {
    float a = x0t[h * 32 + i];
    const float* x1r = x1t + h * 32;
    const float* er  = etf + h * 16;
    float4 v;
    v.x = a * x1r[j0 + 0] * er[t0];
    v.y = a * x1r[j0 + 1] * er[t1];
    v.z = a * x1r[j0 + 2] * er[t2];
    v.w = a * x1r[j0 + 3] * er[t3];
    *(float4*)(outg + h * 1024 + tid * 4) = v;
  }
}

// ---------------------------------------------------------------------------
// KF v21 (fused conv layer, 8 waves / 512 threads): grid G*4 (same slab
// decomposition), launch_bounds(512, 2). Per-element math identical to the
// verified v16/v20 lineage -> absmax 0. Rationale: 3 rounds plateaued at
// ~60us/dispatch, latency-bound at 8 waves/CU (grid-capped 2 WG/CU of 4
// waves). 8-wave WGs double waves/CU to 16 IF the allocator stays <=128
// VGPR (it has for 5 rounds; acc halves to [2][8]=64, live ~110-125).
// (512,2) guarantees 1 WG/CU resident (256-reg budget, no forced squeeze
// -> no spill; v9/v12's spills were the runtime-indexed-acc bug + (512,4)
// forcing 64 regs, both absent here). Worst case: >128 regs -> 1 WG/CU =
// today's 8 waves = neutral.
// Wave mapping: wave wv owns i-row wv (p = wv*32 + pt*16 + x, pt<2);
// stages 4 k-rows/chunk (async gload_lds raw-f32, v20 verified); msg 4
// planes/round. Phase C fully unrolled (static acc idx).
// LDS: Xs dbuf 2x32896 (Yp 35.3KB aliases) + c8 1K + epk 9.2K = 76 KB.
// ---------------------------------------------------------------------------
template <int POOL>
__global__ __launch_bounds__(512, 2) void k_fused(
    float* __restrict__ Xp,
    const unsigned* __restrict__ Whi, const unsigned* __restrict__ Wlo,
    const float* __restrict__ bcl, const float* __restrict__ gcl,
    const float* __restrict__ ccl,
    const int* __restrict__ ea_idx, const int* __restrict__ adj,
    const float* __restrict__ emb_ea, float* __restrict__ Pm) {
  int g = blockIdx.x >> 2, oct = blockIdx.x & 3;
  int tid = threadIdx.x;
  int lane = tid & 63, wv = tid >> 6;            // wv 0..7
  int x = lane & 15, quad = lane >> 4;

  __shared__ __align__(16) unsigned char u_raw[65792];
  // phase A: Xs[2] raw f32 chunks, each 32 rows x 257 floats (1028 B/row)
  // phase C: Yp packed Y pairs, [32 planes][276 words], rows stride 34
  unsigned* Yp = (unsigned*)u_raw;
  __shared__ unsigned char c8[1024];
  __shared__ unsigned epk[128 * 18];   // packed f16 hi|lo edge values

  // ---- stage A-codes and pre-packed edge table
  if (tid < 256) {
    int4 ev = ((const int4*)(ea_idx + (size_t)g * 1024))[tid];
    int4 av = ((const int4*)(adj   + (size_t)g * 1024))[tid];
    uchar4 c;
    c.x = av.x ? (unsigned char)ev.x : (unsigned char)16;
    c.y = av.y ? (unsigned char)ev.y : (unsigned char)16;
    c.z = av.z ? (unsigned char)ev.z : (unsigned char)16;
    c.w = av.w ? (unsigned char)ev.w : (unsigned char)16;
    ((uchar4*)c8)[tid] = c;
  }
#pragma unroll
  for (int it = 0; it < 4; it++) {
    int idx = it * 512 + tid;                    // 0..2047 (e 0..15)
    int e = idx >> 7, h = idx & 127;
    epk[h * 18 + e] = packf16(emb_ea[e * 128 + h]);
  }
  if (tid < 128) epk[tid * 18 + 16] = 0u;        // packf16(0) == 0

  // ---- phase A: mlp. acc[pt][hh]; p = wv*32+pt*16+x, h = hh*16+quad*4+r
  f32x4 acc[2][8];
#pragma unroll
  for (int hh = 0; hh < 8; hh++) {
    float4 b4 = *(const float4*)(bcl + hh * 16 + quad * 4);
    f32x4 bi; bi[0] = b4.x; bi[1] = b4.y; bi[2] = b4.z; bi[3] = b4.w;
    acc[0][hh] = bi;
    acc[1][hh] = bi;
  }
  const float* Xg = Xp + ((size_t)g << 17) + oct * 256;

  // async stage: wave wv copies k-rows wv*4..+3 of chunk c into buffer Xsb.
  auto STAGE = [&](unsigned char* Xsb, int c) {
#pragma unroll
    for (int m = 0; m < 4; m++) {
      const float* gsrc = Xg + (size_t)(c * 32 + wv * 4 + m) * 1024 + lane * 4;
      unsigned char* ldst = Xsb + (wv * 4 + m) * 1028;
      __builtin_amdgcn_global_load_lds(
          (const __attribute__((address_space(1))) unsigned*)gsrc,
          (__attribute__((address_space(3))) unsigned*)ldst, 16, 0, 0);
    }
  };

  STAGE(u_raw, 0);
  __syncthreads();
#pragma unroll
  for (int c = 0; c < 4; c++) {
    const float* Tc = (const float*)(u_raw + ((c & 1) ? 32896 : 0));
    if (c < 3) STAGE(u_raw + (((c + 1) & 1) ? 32896 : 0), c + 1);
    // ---- B fragment pairs for the 2 p-tiles: read raw f32, pack in regs
    H8 bh[2], bl[2];
#pragma unroll
    for (int pt = 0; pt < 2; pt++) {
      int p = wv * 32 + pt * 16 + x;
#pragma unroll
      for (int n = 0; n < 4; n++) {
        int k2 = quad * 8 + n * 2;
        unsigned p0 = packf16(Tc[k2 * 257 + p]);
        unsigned p1 = packf16(Tc[(k2 + 1) * 257 + p]);
        bh[pt].u[n] = __builtin_amdgcn_perm(p1, p0, 0x05040100u);
        bl[pt].u[n] = __builtin_amdgcn_perm(p1, p0, 0x07060302u);
      }
    }
    // ---- stream A pairs over 8 h-tiles from global Whi/Wlo (L2)
#pragma unroll
    for (int hh = 0; hh < 8; hh++) {
      int hrow = hh * 16 + x;
      H8 ah, al;
      *(uint4*)&ah.u[0] = *(const uint4*)(Whi + (size_t)hrow * 64 + c * 16 + quad * 4);
      *(uint4*)&al.u[0] = *(const uint4*)(Wlo + (size_t)hrow * 64 + c * 16 + quad * 4);
#pragma unroll
      for (int pt = 0; pt < 2; pt++) {
        acc[pt][hh] = __builtin_amdgcn_mfma_f32_16x16x32_f16(ah.v, bh[pt].v, acc[pt][hh], 0, 0, 0);
        acc[pt][hh] = __builtin_amdgcn_mfma_f32_16x16x32_f16(ah.v, bl[pt].v, acc[pt][hh], 0, 0, 0);
        acc[pt][hh] = __builtin_amdgcn_mfma_f32_16x16x32_f16(al.v, bh[pt].v, acc[pt][hh], 0, 0, 0);
      }
    }
    if (c < 3) __syncthreads();
  }

  // ---- phase B: LN + relu in registers (acc := Y)
  {
    float gm[2], gr[2];
#pragma unroll
    for (int pt = 0; pt < 2; pt++) {
      float s = 0.f;
#pragma unroll
      for (int hh = 0; hh < 8; hh++)
#pragma unroll
        for (int r = 0; r < 4; r++) s += acc[pt][hh][r];
      s += __shfl_xor(s, 16);
      s += __shfl_xor(s, 32);
      float m = s * (1.f / 128.f);
      float qv = 0.f;
#pragma unroll
      for (int hh = 0; hh < 8; hh++)
#pragma unroll
        for (int r = 0; r < 4; r++) { float d = acc[pt][hh][r] - m; qv += d * d; }
      qv += __shfl_xor(qv, 16);
      qv += __shfl_xor(qv, 32);
      gm[pt] = m;
      gr[pt] = rsqrtf(qv * (1.f / 128.f) + 1e-5f);
    }
#pragma unroll
    for (int hh = 0; hh < 8; hh++) {
      float4 g4 = *(const float4*)(gcl + hh * 16 + quad * 4);
      float4 c4 = *(const float4*)(ccl + hh * 16 + quad * 4);
      float ga[4] = {g4.x, g4.y, g4.z, g4.w};
      float ca[4] = {c4.x, c4.y, c4.z, c4.w};
#pragma unroll
      for (int r = 0; r < 4; r++)
#pragma unroll
        for (int pt = 0; pt < 2; pt++)
          acc[pt][hh][r] = fmaxf((acc[pt][hh][r] - gm[pt]) * gr[pt] * ga[r] + ca[r], 0.f);
    }
  }

  // ---- phase C: 4 rounds x 32 planes; msg via MFMA. Wave wv deposits its
  // i-row (ii = wv, kk = pt*16+x) and handles planes hrel = wv*4..+4.
  int xi = x & 7;
#pragma unroll
  for (int q = 0; q < 4; q++) {
    __syncthreads();   // Yp region free (Xs reads done / prev round done)
#pragma unroll
    for (int hq = 0; hq < 2; hq++) {
      int hh = q * 2 + hq;
#pragma unroll
      for (int pt = 0; pt < 2; pt++) {
        int kk = pt * 16 + x;
#pragma unroll
        for (int r = 0; r < 4; r++)
          Yp[(hq * 16 + quad * 4 + r) * 276 + wv * 34 + kk] = packf16(acc[pt][hh][r]);
      }
    }
    __syncthreads();
#pragma unroll 1
    for (int pl = 0; pl < 4; pl++) {
      int hrel = wv * 4 + pl;
      int h = q * 32 + hrel;
      // B-op (Y) fragments: col i = x, k = quad*8 + n*2 (+1)
      H8 ybh, ybl;
#pragma unroll
      for (int n = 0; n < 4; n++) {
        uint2 d = *(const uint2*)&Yp[hrel * 276 + x * 34 + quad * 8 + n * 2];
        ybh.u[n] = __builtin_amdgcn_perm(d.y, d.x, 0x05040100u);
        ybl.u[n] = __builtin_amdgcn_perm(d.y, d.x, 0x07060302u);
      }
      float* xrow = Xp + (((size_t)(g * 128 + h)) << 10) + (oct * 8 + xi) * 32;
      float psum = 0.f;
#pragma unroll
      for (int jt = 0; jt < 2; jt++) {
        // A-op (edge^T) fragments via pre-packed epk
        H8 ah, al;
#pragma unroll
        for (int n = 0; n < 4; n++) {
          int k = quad * 8 + n * 2;
          unsigned c0 = c8[k * 32 + jt * 16 + x];
          unsigned c1 = c8[(k + 1) * 32 + jt * 16 + x];
          unsigned p0 = epk[h * 18 + c0];
          unsigned p1 = epk[h * 18 + c1];
          ah.u[n] = __builtin_amdgcn_perm(p1, p0, 0x05040100u);
          al.u[n] = __builtin_amdgcn_perm(p1, p0, 0x07060302u);
        }
        float4 xv = *(const float4*)(xrow + jt * 16 + quad * 4);
        f32x4 cfr; cfr[0] = xv.x; cfr[1] = xv.y; cfr[2] = xv.z; cfr[3] = xv.w;
        cfr = __builtin_amdgcn_mfma_f32_16x16x32_f16(ah.v, ybh.v, cfr, 0, 0, 0);
        cfr = __builtin_amdgcn_mfma_f32_16x16x32_f16(ah.v, ybl.v, cfr, 0, 0, 0);
        cfr = __builtin_amdgcn_mfma_f32_16x16x32_f16(al.v, ybh.v, cfr, 0, 0, 0);
        if (!POOL) {
          if (x < 8) {
            float4 o; o.x = cfr[0]; o.y = cfr[1]; o.z = cfr[2]; o.w = cfr[3];
            *(float4*)(xrow + jt * 16 + quad * 4) = o;
          }
        } else {
          psum += cfr[0] + cfr[1] + cfr[2] + cfr[3];
        }
      }
      if (POOL) {
        psum += __shfl_xor(psum, 16);
        psum += __shfl_xor(psum, 32);
        if (quad == 0 && x < 8)
          Pm[(size_t)g * 4096 + h * 32 + oct * 8 + x] = psum * 0.03125f;
      }
    }
  }
}

// ---------------------------------------------------------------------------
// T v3: reads pooled means from Pm[g][h][i] (written by k_fused<1>).
// ---------------------------------------------------------------------------
__global__ __launch_bounds__(256) void k_tail(
    const float* __restrict__ Pm,
    const float* __restrict__ Wp, const float* __restrict__ bp,
    const float* __restrict__ gp, const float* __restrict__ cp,
    const float* __restrict__ Wq1, const float* __restrict__ bq1,
    const float* __restrict__ gq1, const float* __restrict__ cq1,
    const float* __restrict__ Wq2, const float* __restrict__ bq2,
    float* __restrict__ out) {
  int g = blockIdx.x, tid = threadIdx.x;
  __shared__ float xs_s[32 * 132];
  __shared__ float y_s[32 * 132];
  __shared__ float stat_m[1], stat_r[1];
  __shared__ float hg_s[128];
  __shared__ float q_s[128];
  __shared__ float redf[128];
  const float* Pg = Pm + (size_t)g * 4096;
  {
    int h = tid >> 1, i0 = (tid & 1) * 16;
    const float4* src = (const float4*)(Pg + h * 32 + i0);
    float4 v0 = src[0], v1 = src[1], v2 = src[2], v3 = src[3];
    xs_s[(i0 +  0) * 132 + h] = v0.x; xs_s[(i0 +  1) * 132 + h] = v0.y;
    xs_s[(i0 +  2) * 132 + h] = v0.z; xs_s[(i0 +  3) * 132 + h] = v0.w;
    xs_s[(i0 +  4) * 132 + h] = v1.x; xs_s[(i0 +  5) * 132 + h] = v1.y;
    xs_s[(i0 +  6) * 132 + h] = v1.z; xs_s[(i0 +  7) * 132 + h] = v1.w;
    xs_s[(i0 +  8) * 132 + h] = v2.x; xs_s[(i0 +  9) * 132 + h] = v2.y;
    xs_s[(i0 + 10) * 132 + h] = v2.z; xs_s[(i0 + 11) * 132 + h] = v2.w;
    xs_s[(i0 + 12) * 132 + h] = v3.x; xs_s[(i0 + 13) * 132 + h] = v3.y;
    xs_s[(i0 + 14) * 132 + h] = v3.z; xs_s[(i0 + 15) * 132 + h] = v3.w;
  }
  __syncthreads();
  int i_ = tid >> 3, h0 = (tid & 7) * 16;
  float acc[16];
#pragma unroll
  for (int hh = 0; hh < 16; hh++) acc[hh] = bp[h0 + hh];
  for (int k = 0; k < 128; k++) {
    float a = xs_s[i_ * 132 + k];
    const float4* wr = (const float4*)(Wp + k * 128 + h0);
    float4 w0 = wr[0], w1 = wr[1], w2 = wr[2], w3 = wr[3];
    acc[0]  += a * w0.x; acc[1]  += a * w0.y; acc[2]  += a * w0.z; acc[3]  += a * w0.w;
    acc[4]  += a * w1.x; acc[5]  += a * w1.y; acc[6]  += a * w1.z; acc[7]  += a * w1.w;
    acc[8]  += a * w2.x; acc[9]  += a * w2.y; acc[10] += a * w2.z; acc[11] += a * w2.w;
    acc[12] += a * w3.x; acc[13] += a * w3.y; acc[14] += a * w3.z; acc[15] += a * w3.w;
  }
  {
    float s = 0.f;
#pragma unroll
    for (int hh = 0; hh < 16; hh++) s += acc[hh];
    s += __shfl_xor(s, 1); s += __shfl_xor(s, 2); s += __shfl_xor(s, 4);
    float m = s * (1.f / 128.f);
    float qv = 0.f;
#pragma unroll
    for (int hh = 0; hh < 16; hh++) { float d = acc[hh] - m; qv += d * d; }
    qv += __shfl_xor(qv, 1); qv += __shfl_xor(qv, 2); qv += __shfl_xor(qv, 4);
    float r = rsqrtf(qv * (1.f / 128.f) + 1e-5f);
#pragma unroll
    for (int hh = 0; hh < 16; hh++) {
      int hc = h0 + hh;
      float v = (acc[hh] - m) * r * gp[hc] + cp[hc];
      y_s[i_ * 132 + hc] = fmaxf(v, 0.f);
    }
  }
  __syncthreads();
  if (tid < 128) {
    float s = 0.f;
#pragma unroll
    for (int ii = 0; ii < 32; ii++) s += y_s[ii * 132 + tid];
    hg_s[tid] = s;
  }
  __syncthreads();
  if (tid < 128) {
    float a = bq1[tid];
    for (int k = 0; k < 128; k++) a += hg_s[k] * Wq1[k * 128 + tid];
    q_s[tid] = a;
  }
  __syncthreads();
  if (tid < 64) {
    float a = q_s[tid], b = q_s[tid + 64];
    float s = a + b;
#pragma unroll
    for (int o = 1; o < 64; o <<= 1) s += __shfl_xor(s, o);
    float m = s * (1.f / 128.f);
    float d1 = a - m, d2 = b - m;
    float qq = d1 * d1 + d2 * d2;
#pragma unroll
    for (int o = 1; o < 64; o <<= 1) qq += __shfl_xor(qq, o);
    if (tid == 0) { stat_m[0] = m; stat_r[0] = rsqrtf(qq * (1.f / 128.f) + 1e-5f); }
  }
  __syncthreads();
  if (tid < 128) {
    float v = (q_s[tid] - stat_m[0]) * stat_r[0] * gq1[tid] + cq1[tid];
    v = fmaxf(v, 0.f);
    redf[tid] = v * Wq2[tid];
  }
  __syncthreads();
  if (tid < 64) {
    float s = redf[tid] + redf[tid + 64];
#pragma unroll
    for (int o = 1; o < 64; o <<= 1) s += __shfl_xor(s, o);
    if (tid == 0) out[g] = s + bq2[0];
  }
}

// ---------------------------------------------------------------------------
extern "C" void kernel_launch(void* const* d_in, const int* in_sizes, int n_in,
                              void* d_out, int out_size, void* d_ws, size_t ws_size,
                              hipStream_t stream) {
  const int*   x_idx  = (const int*)d_in[0];
  const int*   ea_idx = (const int*)d_in[1];
  const int*   tf_idx = (const int*)d_in[2];
  const int*   adj    = (const int*)d_in[3];
  const float* emb_x  = (const float*)d_in[4];
  const float* emb_ea = (const float*)d_in[5];
  const float* emb_tf = (const float*)d_in[6];
  const float* W0  = (const float*)d_in[7];
  const float* b0  = (const float*)d_in[8];
  const float* W1  = (const float*)d_in[9];
  const float* b1  = (const float*)d_in[10];
  const float* Wc  = (const float*)d_in[11];
  const float* bc  = (const float*)d_in[12];
  const float* gc  = (const float*)d_in[13];
  const float* cc  = (const float*)d_in[14];
  const float* Wp  = (const float*)d_in[15];
  const float* bp  = (const float*)d_in[16];
  const float* gp  = (const float*)d_in[17];
  const float* cp  = (const float*)d_in[18];
  const float* Wq1 = (const float*)d_in[19];
  const float* bq1 = (const float*)d_in[20];
  const float* gq1 = (const float*)d_in[21];
  const float* cq1 = (const float*)d_in[22];
  const float* Wq2 = (const float*)d_in[23];
  const float* bq2 = (const float*)d_in[24];
  float* out = (float*)d_out;

  float* ws = (float*)d_ws;
  float* Xp = ws;
  float* Pm = ws + (size_t)16777216;
  float* P0 = ws + (size_t)33554432;
  float* P1 = P0 + 4096;
  unsigned* Whi = (unsigned*)(ws + (size_t)33562624);  // 6*128*64 u32
  unsigned* Wlo = Whi + 49152;

  k_head<<<194, 256, 0, stream>>>(emb_x, W0, b0, P0, W1, b1, P1, Wc, Whi, Wlo);
  k_buildX<<<G, 256, 0, stream>>>(x_idx, tf_idx, P0, P1, emb_tf, Xp);
  for (int l = 0; l < L; l++) {
    if (l == L - 1)
      k_fused<1><<<G * 4, 512, 0, stream>>>(Xp, Whi + (size_t)l * 8192,
                                            Wlo + (size_t)l * 8192,
                                            bc + l * H, gc + l * H, cc + l * H,
                                            ea_idx, adj, emb_ea, Pm);
    else
      k_fused<0><<<G * 4, 512, 0, stream>>>(Xp, Whi + (size_t)l * 8192,
                                            Wlo + (size_t)l * 8192,
                                            bc + l * H, gc + l * H, cc + l * H,
                                            ea_idx, adj, emb_ea, Pm);
  }
  k_tail<<<G, 256, 0, stream>>>(Pm, Wp, bp, gp, cp, Wq1, bq1, gq1, cq1, Wq2, bq2, out);
}

// Round 21
// 528.565 us; speedup vs baseline: 1.3081x; 1.3081x over previous
//
#include <hip/hip_runtime.h>

#define G 128
#define N 32
#define H 128
#define L 6

typedef _Float16 half8 __attribute__((ext_vector_type(8)));
typedef float f32x4 __attribute__((ext_vector_type(4)));

union H8 { unsigned u[4]; half8 v; };

__device__ inline unsigned short f16_bits(_Float16 h) {
  union { _Float16 f; unsigned short u; } c; c.f = h; return c.u;
}

// pack fp32 -> (f16 hi) | (f16 lo)<<16, hi = rne(x), lo = rne(x - hi)
__device__ inline unsigned packf16(float x) {
  _Float16 hi = (_Float16)x;
  _Float16 lo = (_Float16)(x - (float)hi);
  return (unsigned)f16_bits(hi) | ((unsigned)f16_bits(lo) << 16);
}

// ---------------------------------------------------------------------------
// HEAD (merged E1 + PW): blocks 0-1 emb mm; blocks 2-193 pack Wc.
// ---------------------------------------------------------------------------
__global__ __launch_bounds__(256) void k_head(
    const float* __restrict__ emb_x,
    const float* __restrict__ W0, const float* __restrict__ b0, float* __restrict__ P0,
    const float* __restrict__ W1, const float* __restrict__ b1, float* __restrict__ P1,
    const float* __restrict__ Wc, unsigned* __restrict__ Whi,
    unsigned* __restrict__ Wlo) {
  int tid = threadIdx.x;
  if (blockIdx.x >= 2) {
    int o  = (blockIdx.x - 2) * 256 + tid;      // 0 .. 49151
    int kp = o & 63;
    int h  = (o >> 6) & 127;
    int l  = o >> 13;
    const float* Wl = Wc + (size_t)l * 16384;
    float a = Wl[(2 * kp) * 128 + h];
    float b = Wl[(2 * kp + 1) * 128 + h];
    unsigned pa = packf16(a), pb = packf16(b);
    Whi[o] = __builtin_amdgcn_perm(pb, pa, 0x05040100u);
    Wlo[o] = __builtin_amdgcn_perm(pb, pa, 0x07060302u);
    return;
  }
  const float* W = blockIdx.x ? W1 : W0;
  const float* b = blockIdx.x ? b1 : b0;
  float*       P = blockIdx.x ? P1 : P0;
  __shared__ float embs_t[128 * 32];   // [k][i]
  {
    int i = tid & 31, k0 = (tid >> 5) * 16;
    const float* src = emb_x + i * 128 + k0;
#pragma unroll
    for (int m = 0; m < 16; m++) embs_t[(k0 + m) * 32 + i] = src[m];
  }
  __syncthreads();
  int i  = tid >> 3;
  int h0 = (tid & 7) * 16;
  float acc[16];
#pragma unroll
  for (int hh = 0; hh < 16; hh++) acc[hh] = b[h0 + hh];
  for (int k = 0; k < 128; k++) {
    float a = embs_t[k * 32 + i];
    const float4* wr = (const float4*)(W + k * 128 + h0);
    float4 w0 = wr[0], w1 = wr[1], w2 = wr[2], w3 = wr[3];
    acc[0]  += a * w0.x; acc[1]  += a * w0.y; acc[2]  += a * w0.z; acc[3]  += a * w0.w;
    acc[4]  += a * w1.x; acc[5]  += a * w1.y; acc[6]  += a * w1.z; acc[7]  += a * w1.w;
    acc[8]  += a * w2.x; acc[9]  += a * w2.y; acc[10] += a * w2.z; acc[11] += a * w2.w;
    acc[12] += a * w3.x; acc[13] += a * w3.y; acc[14] += a * w3.z; acc[15] += a * w3.w;
  }
  float4* dst = (float4*)(P + i * 128 + h0);
  dst[0] = make_float4(acc[0], acc[1], acc[2], acc[3]);
  dst[1] = make_float4(acc[4], acc[5], acc[6], acc[7]);
  dst[2] = make_float4(acc[8], acc[9], acc[10], acc[11]);
  dst[3] = make_float4(acc[12], acc[13], acc[14], acc[15]);
}

// ---------------------------------------------------------------------------
// E2: build X h-planar: Xp[g][h][i*32+j]. One WG per graph.
// ---------------------------------------------------------------------------
__global__ __launch_bounds__(256) void k_buildX(
    const int* __restrict__ x_idx, const int* __restrict__ tf_idx,
    const float* __restrict__ P0, const float* __restrict__ P1,
    const float* __restrict__ emb_tf, float* __restrict__ Xp) {
  int g = blockIdx.x, tid = threadIdx.x;
  __shared__ float x0t[128 * 32];
  __shared__ float x1t[128 * 32];
  __shared__ float etf[128 * 16];
  __shared__ int   tfs[1024];
  {
    int i = tid & 31, h0 = (tid >> 5) * 16;
    int r = x_idx[g * 32 + i];
    const float* s0 = P0 + r * 128 + h0;
    const float* s1 = P1 + r * 128 + h0;
#pragma unroll
    for (int m = 0; m < 16; m++) {
      x0t[(h0 + m) * 32 + i] = s0[m];
      x1t[(h0 + m) * 32 + i] = s1[m];
    }
  }
  {
    int t = tid & 15, h0 = (tid >> 4) * 8;
    const float* s = emb_tf + t * 128 + h0;
#pragma unroll
    for (int m = 0; m < 8; m++) etf[(h0 + m) * 16 + t] = s[m];
  }
  ((int4*)tfs)[tid] = ((const int4*)(tf_idx + (size_t)g * 1024))[tid];
  __syncthreads();
  int i = tid >> 3, j0 = (tid & 7) * 4;
  int t0 = tfs[i * 32 + j0 + 0], t1 = tfs[i * 32 + j0 + 1];
  int t2 = tfs[i * 32 + j0 + 2], t3 = tfs[i * 32 + j0 + 3];
  float* outg = Xp + ((size_t)g << 17);
  for (int h = 0; h < 128; h++) {
    float a = x0t[h * 32 + i];
    const float* x1r = x1t + h * 32;
    const float* er  = etf + h * 16;
    float4 v;
    v.x = a * x1r[j0 + 0] * er[t0];
    v.y = a * x1r[j0 + 1] * er[t1];
    v.z = a * x1r[j0 + 2] * er[t2];
    v.w = a * x1r[j0 + 3] * er[t3];
    *(float4*)(outg + h * 1024 + tid * 4) = v;
  }
}

// ---------------------------------------------------------------------------
// KF v16 (fused conv layer, the round-15/18 verified kernel: 527us total,
// absmax 0). Best-measured configuration, locked in after rounds 16-20
// falsified mono-kernel fusion, residual prefetch, async staging (neutral),
// and 8-wave WGs.
//  - phase A: dbuf mlp (f16 hi/lo 3-MFMA, Whi/Wlo direct from L2)
//  - phase B: in-register LN+relu
//  - phase C: 4 rounds x 32 planes, msg via MFMA with pre-packed epk
//    edge table (Yp stride 34, c8 in-loop).
// grid G*4, 256 thr, launch_bounds(256,2). LDS 74.2KB -> 2 WGs/CU.
// ---------------------------------------------------------------------------
template <int POOL>
__global__ __launch_bounds__(256, 2) void k_fused(
    float* __restrict__ Xp,
    const unsigned* __restrict__ Whi, const unsigned* __restrict__ Wlo,
    const float* __restrict__ bcl, const float* __restrict__ gcl,
    const float* __restrict__ ccl,
    const int* __restrict__ ea_idx, const int* __restrict__ adj,
    const float* __restrict__ emb_ea, float* __restrict__ Pm) {
  int g = blockIdx.x >> 2, oct = blockIdx.x & 3;
  int tid = threadIdx.x;
  int lane = tid & 63, wv = tid >> 6;
  int x = lane & 15, quad = lane >> 4;

  __shared__ __align__(16) unsigned char u_raw[65536];
  // phase A: Xs[2][8192 words] (double buffer, 32KB each)
  // phase C: Yp packed Y pairs, [32 planes][276 words], rows stride 34
  unsigned* Yp = (unsigned*)u_raw;
  __shared__ unsigned char c8[1024];
  __shared__ unsigned epk[128 * 18];   // packed f16 hi|lo edge values

  // ---- stage A-codes and pre-packed edge table
  {
    int4 ev = ((const int4*)(ea_idx + (size_t)g * 1024))[tid];
    int4 av = ((const int4*)(adj   + (size_t)g * 1024))[tid];
    uchar4 c;
    c.x = av.x ? (unsigned char)ev.x : (unsigned char)16;
    c.y = av.y ? (unsigned char)ev.y : (unsigned char)16;
    c.z = av.z ? (unsigned char)ev.z : (unsigned char)16;
    c.w = av.w ? (unsigned char)ev.w : (unsigned char)16;
    ((uchar4*)c8)[tid] = c;
  }
#pragma unroll
  for (int it = 0; it < 8; it++) {
    int idx = it * 256 + tid;
    int e = idx >> 7, h = idx & 127;
    epk[h * 18 + e] = packf16(emb_ea[e * 128 + h]);
  }
  if (tid < 128) epk[tid * 18 + 16] = 0u;   // packf16(0) == 0

  // ---- phase A: mlp. acc[pt][hh]; p = wv*64+pt*16+x, h = hh*16+quad*4+r
  f32x4 acc[4][8];
#pragma unroll
  for (int hh = 0; hh < 8; hh++) {
    float4 b4 = *(const float4*)(bcl + hh * 16 + quad * 4);
    f32x4 bi; bi[0] = b4.x; bi[1] = b4.y; bi[2] = b4.z; bi[3] = b4.w;
#pragma unroll
    for (int pt = 0; pt < 4; pt++) acc[pt][hh] = bi;
  }
  const float* Xg = Xp + ((size_t)g << 17) + oct * 256;

  auto STAGE = [&](unsigned* Xsb, int c) {
    unsigned pk[8][4];
#pragma unroll
    for (int m = 0; m < 8; m++) {
      float4 v = *(const float4*)(Xg + (size_t)(c * 32 + wv * 8 + m) * 1024 + lane * 4);
      pk[m][0] = packf16(v.x); pk[m][1] = packf16(v.y);
      pk[m][2] = packf16(v.z); pk[m][3] = packf16(v.w);
    }
#pragma unroll
    for (int r = 0; r < 4; r++) {
      int p = 4 * lane + r;
      int sw = (p >> 2) & 7;
#pragma unroll
      for (int B2 = 0; B2 < 2; B2++) {
        int B = wv * 2 + B2;
        uint4 q4;
        q4.x = pk[B2 * 4 + 0][r]; q4.y = pk[B2 * 4 + 1][r];
        q4.z = pk[B2 * 4 + 2][r]; q4.w = pk[B2 * 4 + 3][r];
        *(uint4*)&Xsb[p * 32 + ((B ^ sw) << 2)] = q4;
      }
    }
  };

  STAGE((unsigned*)u_raw, 0);
  __syncthreads();
#pragma unroll
  for (int c = 0; c < 4; c++) {
    unsigned* Xcur = (unsigned*)(u_raw + ((c & 1) ? 32768 : 0));
    if (c < 3) STAGE((unsigned*)(u_raw + (((c + 1) & 1) ? 32768 : 0)), c + 1);
    H8 bh[4], bl[4];
#pragma unroll
    for (int pt = 0; pt < 4; pt++) {
      int p = wv * 64 + pt * 16 + x;
      int sw = (p >> 2) & 7;
#pragma unroll
      for (int n = 0; n < 4; n++) {
        int k = quad * 8 + n * 2;
        uint2 d = *(const uint2*)&Xcur[p * 32 + (((k >> 2) ^ sw) << 2) + (k & 3)];
        bh[pt].u[n] = __builtin_amdgcn_perm(d.y, d.x, 0x05040100u);
        bl[pt].u[n] = __builtin_amdgcn_perm(d.y, d.x, 0x07060302u);
      }
    }
#pragma unroll
    for (int hh = 0; hh < 8; hh++) {
      int hrow = hh * 16 + x;
      H8 ah, al;
      *(uint4*)&ah.u[0] = *(const uint4*)(Whi + (size_t)hrow * 64 + c * 16 + quad * 4);
      *(uint4*)&al.u[0] = *(const uint4*)(Wlo + (size_t)hrow * 64 + c * 16 + quad * 4);
#pragma unroll
      for (int pt = 0; pt < 4; pt++) {
        acc[pt][hh] = __builtin_amdgcn_mfma_f32_16x16x32_f16(ah.v, bh[pt].v, acc[pt][hh], 0, 0, 0);
        acc[pt][hh] = __builtin_amdgcn_mfma_f32_16x16x32_f16(ah.v, bl[pt].v, acc[pt][hh], 0, 0, 0);
        acc[pt][hh] = __builtin_amdgcn_mfma_f32_16x16x32_f16(al.v, bh[pt].v, acc[pt][hh], 0, 0, 0);
      }
    }
    if (c < 3) __syncthreads();
  }

  // ---- phase B: LN + relu in registers (acc := Y)
  {
    float gm[4], gr[4];
#pragma unroll
    for (int pt = 0; pt < 4; pt++) {
      float s = 0.f;
#pragma unroll
      for (int hh = 0; hh < 8; hh++)
#pragma unroll
        for (int r = 0; r < 4; r++) s += acc[pt][hh][r];
      s += __shfl_xor(s, 16);
      s += __shfl_xor(s, 32);
      float m = s * (1.f / 128.f);
      float qv = 0.f;
#pragma unroll
      for (int hh = 0; hh < 8; hh++)
#pragma unroll
        for (int r = 0; r < 4; r++) { float d = acc[pt][hh][r] - m; qv += d * d; }
      qv += __shfl_xor(qv, 16);
      qv += __shfl_xor(qv, 32);
      gm[pt] = m;
      gr[pt] = rsqrtf(qv * (1.f / 128.f) + 1e-5f);
    }
#pragma unroll
    for (int hh = 0; hh < 8; hh++) {
      float4 g4 = *(const float4*)(gcl + hh * 16 + quad * 4);
      float4 c4 = *(const float4*)(ccl + hh * 16 + quad * 4);
      float ga[4] = {g4.x, g4.y, g4.z, g4.w};
      float ca[4] = {c4.x, c4.y, c4.z, c4.w};
#pragma unroll
      for (int r = 0; r < 4; r++)
#pragma unroll
        for (int pt = 0; pt < 4; pt++)
          acc[pt][hh][r] = fmaxf((acc[pt][hh][r] - gm[pt]) * gr[pt] * ga[r] + ca[r], 0.f);
    }
  }

  // ---- phase C: 4 rounds x 32 planes; msg via MFMA.
  int xi = x & 7;
#pragma unroll
  for (int q = 0; q < 4; q++) {
    __syncthreads();   // Yp region free (Xs reads done / prev round done)
#pragma unroll
    for (int hq = 0; hq < 2; hq++) {
      int hh = q * 2 + hq;
#pragma unroll
      for (int pt = 0; pt < 4; pt++) {
        int qv = pt * 16 + x;
        int ii = wv * 2 + (qv >> 5);
        int kk = qv & 31;
#pragma unroll
        for (int r = 0; r < 4; r++)
          Yp[(hq * 16 + quad * 4 + r) * 276 + ii * 34 + kk] = packf16(acc[pt][hh][r]);
      }
    }
    __syncthreads();
#pragma unroll 1
    for (int pl = 0; pl < 8; pl++) {
      int hrel = wv * 8 + pl;
      int h = q * 32 + hrel;
      // B-op (Y) fragments: col i = x, k = quad*8 + n*2 (+1)
      H8 ybh, ybl;
#pragma unroll
      for (int n = 0; n < 4; n++) {
        uint2 d = *(const uint2*)&Yp[hrel * 276 + x * 34 + quad * 8 + n * 2];
        ybh.u[n] = __builtin_amdgcn_perm(d.y, d.x, 0x05040100u);
        ybl.u[n] = __builtin_amdgcn_perm(d.y, d.x, 0x07060302u);
      }
      float* xrow = Xp + (((size_t)(g * 128 + h)) << 10) + (oct * 8 + xi) * 32;
      float psum = 0.f;
#pragma unroll
      for (int jt = 0; jt < 2; jt++) {
        // A-op (edge^T) fragments via pre-packed epk
        H8 ah, al;
#pragma unroll
        for (int n = 0; n < 4; n++) {
          int k = quad * 8 + n * 2;
          unsigned c0 = c8[k * 32 + jt * 16 + x];
          unsigned c1 = c8[(k + 1) * 32 + jt * 16 + x];
          unsigned p0 = epk[h * 18 + c0];
          unsigned p1 = epk[h * 18 + c1];
          ah.u[n] = __builtin_amdgcn_perm(p1, p0, 0x05040100u);
          al.u[n] = __builtin_amdgcn_perm(p1, p0, 0x07060302u);
        }
        float4 xv = *(const float4*)(xrow + jt * 16 + quad * 4);
        f32x4 cfr; cfr[0] = xv.x; cfr[1] = xv.y; cfr[2] = xv.z; cfr[3] = xv.w;
        cfr = __builtin_amdgcn_mfma_f32_16x16x32_f16(ah.v, ybh.v, cfr, 0, 0, 0);
        cfr = __builtin_amdgcn_mfma_f32_16x16x32_f16(ah.v, ybl.v, cfr, 0, 0, 0);
        cfr = __builtin_amdgcn_mfma_f32_16x16x32_f16(al.v, ybh.v, cfr, 0, 0, 0);
        if (!POOL) {
          if (x < 8) {
            float4 o; o.x = cfr[0]; o.y = cfr[1]; o.z = cfr[2]; o.w = cfr[3];
            *(float4*)(xrow + jt * 16 + quad * 4) = o;
          }
        } else {
          psum += cfr[0] + cfr[1] + cfr[2] + cfr[3];
        }
      }
      if (POOL) {
        psum += __shfl_xor(psum, 16);
        psum += __shfl_xor(psum, 32);
        if (quad == 0 && x < 8)
          Pm[(size_t)g * 4096 + h * 32 + oct * 8 + x] = psum * 0.03125f;
      }
    }
  }
}

// ---------------------------------------------------------------------------
// T v3: reads pooled means from Pm[g][h][i] (written by k_fused<1>).
// ---------------------------------------------------------------------------
__global__ __launch_bounds__(256) void k_tail(
    const float* __restrict__ Pm,
    const float* __restrict__ Wp, const float* __restrict__ bp,
    const float* __restrict__ gp, const float* __restrict__ cp,
    const float* __restrict__ Wq1, const float* __restrict__ bq1,
    const float* __restrict__ gq1, const float* __restrict__ cq1,
    const float* __restrict__ Wq2, const float* __restrict__ bq2,
    float* __restrict__ out) {
  int g = blockIdx.x, tid = threadIdx.x;
  __shared__ float xs_s[32 * 132];
  __shared__ float y_s[32 * 132];
  __shared__ float stat_m[1], stat_r[1];
  __shared__ float hg_s[128];
  __shared__ float q_s[128];
  __shared__ float redf[128];
  const float* Pg = Pm + (size_t)g * 4096;
  {
    int h = tid >> 1, i0 = (tid & 1) * 16;
    const float4* src = (const float4*)(Pg + h * 32 + i0);
    float4 v0 = src[0], v1 = src[1], v2 = src[2], v3 = src[3];
    xs_s[(i0 +  0) * 132 + h] = v0.x; xs_s[(i0 +  1) * 132 + h] = v0.y;
    xs_s[(i0 +  2) * 132 + h] = v0.z; xs_s[(i0 +  3) * 132 + h] = v0.w;
    xs_s[(i0 +  4) * 132 + h] = v1.x; xs_s[(i0 +  5) * 132 + h] = v1.y;
    xs_s[(i0 +  6) * 132 + h] = v1.z; xs_s[(i0 +  7) * 132 + h] = v1.w;
    xs_s[(i0 +  8) * 132 + h] = v2.x; xs_s[(i0 +  9) * 132 + h] = v2.y;
    xs_s[(i0 + 10) * 132 + h] = v2.z; xs_s[(i0 + 11) * 132 + h] = v2.w;
    xs_s[(i0 + 12) * 132 + h] = v3.x; xs_s[(i0 + 13) * 132 + h] = v3.y;
    xs_s[(i0 + 14) * 132 + h] = v3.z; xs_s[(i0 + 15) * 132 + h] = v3.w;
  }
  __syncthreads();
  int i_ = tid >> 3, h0 = (tid & 7) * 16;
  float acc[16];
#pragma unroll
  for (int hh = 0; hh < 16; hh++) acc[hh] = bp[h0 + hh];
  for (int k = 0; k < 128; k++) {
    float a = xs_s[i_ * 132 + k];
    const float4* wr = (const float4*)(Wp + k * 128 + h0);
    float4 w0 = wr[0], w1 = wr[1], w2 = wr[2], w3 = wr[3];
    acc[0]  += a * w0.x; acc[1]  += a * w0.y; acc[2]  += a * w0.z; acc[3]  += a * w0.w;
    acc[4]  += a * w1.x; acc[5]  += a * w1.y; acc[6]  += a * w1.z; acc[7]  += a * w1.w;
    acc[8]  += a * w2.x; acc[9]  += a * w2.y; acc[10] += a * w2.z; acc[11] += a * w2.w;
    acc[12] += a * w3.x; acc[13] += a * w3.y; acc[14] += a * w3.z; acc[15] += a * w3.w;
  }
  {
    float s = 0.f;
#pragma unroll
    for (int hh = 0; hh < 16; hh++) s += acc[hh];
    s += __shfl_xor(s, 1); s += __shfl_xor(s, 2); s += __shfl_xor(s, 4);
    float m = s * (1.f / 128.f);
    float qv = 0.f;
#pragma unroll
    for (int hh = 0; hh < 16; hh++) { float d = acc[hh] - m; qv += d * d; }
    qv += __shfl_xor(qv, 1); qv += __shfl_xor(qv, 2); qv += __shfl_xor(qv, 4);
    float r = rsqrtf(qv * (1.f / 128.f) + 1e-5f);
#pragma unroll
    for (int hh = 0; hh < 16; hh++) {
      int hc = h0 + hh;
      float v = (acc[hh] - m) * r * gp[hc] + cp[hc];
      y_s[i_ * 132 + hc] = fmaxf(v, 0.f);
    }
  }
  __syncthreads();
  if (tid < 128) {
    float s = 0.f;
#pragma unroll
    for (int ii = 0; ii < 32; ii++) s += y_s[ii * 132 + tid];
    hg_s[tid] = s;
  }
  __syncthreads();
  if (tid < 128) {
    float a = bq1[tid];
    for (int k = 0; k < 128; k++) a += hg_s[k] * Wq1[k * 128 + tid];
    q_s[tid] = a;
  }
  __syncthreads();
  if (tid < 64) {
    float a = q_s[tid], b = q_s[tid + 64];
    float s = a + b;
#pragma unroll
    for (int o = 1; o < 64; o <<= 1) s += __shfl_xor(s, o);
    float m = s * (1.f / 128.f);
    float d1 = a - m, d2 = b - m;
    float qq = d1 * d1 + d2 * d2;
#pragma unroll
    for (int o = 1; o < 64; o <<= 1) qq += __shfl_xor(qq, o);
    if (tid == 0) { stat_m[0] = m; stat_r[0] = rsqrtf(qq * (1.f / 128.f) + 1e-5f); }
  }
  __syncthreads();
  if (tid < 128) {
    float v = (q_s[tid] - stat_m[0]) * stat_r[0] * gq1[tid] + cq1[tid];
    v = fmaxf(v, 0.f);
    redf[tid] = v * Wq2[tid];
  }
  __syncthreads();
  if (tid < 64) {
    float s = redf[tid] + redf[tid + 64];
#pragma unroll
    for (int o = 1; o < 64; o <<= 1) s += __shfl_xor(s, o);
    if (tid == 0) out[g] = s + bq2[0];
  }
}

// ---------------------------------------------------------------------------
extern "C" void kernel_launch(void* const* d_in, const int* in_sizes, int n_in,
                              void* d_out, int out_size, void* d_ws, size_t ws_size,
                              hipStream_t stream) {
  const int*   x_idx  = (const int*)d_in[0];
  const int*   ea_idx = (const int*)d_in[1];
  const int*   tf_idx = (const int*)d_in[2];
  const int*   adj    = (const int*)d_in[3];
  const float* emb_x  = (const float*)d_in[4];
  const float* emb_ea = (const float*)d_in[5];
  const float* emb_tf = (const float*)d_in[6];
  const float* W0  = (const float*)d_in[7];
  const float* b0  = (const float*)d_in[8];
  const float* W1  = (const float*)d_in[9];
  const float* b1  = (const float*)d_in[10];
  const float* Wc  = (const float*)d_in[11];
  const float* bc  = (const float*)d_in[12];
  const float* gc  = (const float*)d_in[13];
  const float* cc  = (const float*)d_in[14];
  const float* Wp  = (const float*)d_in[15];
  const float* bp  = (const float*)d_in[16];
  const float* gp  = (const float*)d_in[17];
  const float* cp  = (const float*)d_in[18];
  const float* Wq1 = (const float*)d_in[19];
  const float* bq1 = (const float*)d_in[20];
  const float* gq1 = (const float*)d_in[21];
  const float* cq1 = (const float*)d_in[22];
  const float* Wq2 = (const float*)d_in[23];
  const float* bq2 = (const float*)d_in[24];
  float* out = (float*)d_out;

  float* ws = (float*)d_ws;
  float* Xp = ws;
  float* Pm = ws + (size_t)16777216;
  float* P0 = ws + (size_t)33554432;
  float* P1 = P0 + 4096;
  unsigned* Whi = (unsigned*)(ws + (size_t)33562624);  // 6*128*64 u32
  unsigned* Wlo = Whi + 49152;

  k_head<<<194, 256, 0, stream>>>(emb_x, W0, b0, P0, W1, b1, P1, Wc, Whi, Wlo);
  k_buildX<<<G, 256, 0, stream>>>(x_idx, tf_idx, P0, P1, emb_tf, Xp);
  for (int l = 0; l < L; l++) {
    if (l == L - 1)
      k_fused<1><<<G * 4, 256, 0, stream>>>(Xp, Whi + (size_t)l * 8192,
                                            Wlo + (size_t)l * 8192,
                                            bc + l * H, gc + l * H, cc + l * H,
                                            ea_idx, adj, emb_ea, Pm);
    else
      k_fused<0><<<G * 4, 256, 0, stream>>>(Xp, Whi + (size_t)l * 8192,
                                            Wlo + (size_t)l * 8192,
                                            bc + l * H, gc + l * H, cc + l * H,
                                            ea_idx, adj, emb_ea, Pm);
  }
  k_tail<<<G, 256, 0, stream>>>(Pm, Wp, bp, gp, cp, Wq1, bq1, gq1, cq1, Wq2, bq2, out);
}